// Round 10
// baseline (1009.904 us; speedup 1.0000x reference)
//
#include <hip/hip_runtime.h>
#include <hip/hip_bf16.h>

#define UDIM    256
#define ODIM    128
#define ZDIM    1024
#define NSTEPS  48
#define BM      16
#define THREADS 1024
#define NBLOCKS 256   // 4096 / BM

// ws layout in ushort elements — FP16 bits:
//   KR: [0,       393216)   64 tiles x 12 kc x 64 lanes x 8
//   D : [393216,  425984)   8 tiles x 8 kc x 64 lanes x 8
#define KR_FRAGS 393216
#define D_FRAGS  32768
// LDS-cached kc0 of KR: 64 tiles x 64 lanes x 8 ushort = 64 KB
#define KR0_FRAGS 32768

// sA cols: [0,128)=x, [128,384)=h buf0, [384,640)=h buf1, pad to 648
// (row = 1296 B, 16B-aligned so ds_read_b128 stays legal).
#define SA_W 648

typedef _Float16 f16x8 __attribute__((ext_vector_type(8)));
typedef float    f32x4 __attribute__((ext_vector_type(4)));

__device__ __forceinline__ ushort f2h_bits(float v) {
    _Float16 h = (_Float16)v;          // v_cvt_f16_f32, RNE
    return *reinterpret_cast<ushort*>(&h);
}
__device__ __forceinline__ float sigmoid_f(float x) {
    return 1.0f / (1.0f + __expf(-x));
}
__device__ __forceinline__ float tanh_f(float x) {
    return 1.0f - 2.0f / (__expf(2.0f * x) + 1.0f);
}

// ---- prep: pack weights into MFMA B-fragment order, fp16 (round-nearest) ----
__global__ void prep_weights(const float* __restrict__ kernel_w,   // [128,1024]
                             const float* __restrict__ rec_w,      // [256,1024]
                             const float* __restrict__ dense_w,    // [256,128]
                             ushort* __restrict__ ws) {
    int idx = blockIdx.x * blockDim.x + threadIdx.x;
    if (idx < KR_FRAGS) {
        int j  = idx & 7;
        int l  = (idx >> 3) & 63;
        int fc = idx >> 9;          // n*12 + kc
        int kc = fc % 12;
        int n  = fc / 12;
        int k   = kc * 32 + (l >> 4) * 8 + j;
        int col = n * 16 + (l & 15);
        float wv = (k < 128) ? kernel_w[k * ZDIM + col]
                             : rec_w[(k - 128) * ZDIM + col];
        ws[idx] = f2h_bits(wv);
    } else if (idx < KR_FRAGS + D_FRAGS) {
        int e  = idx - KR_FRAGS;
        int j  = e & 7;
        int l  = (e >> 3) & 63;
        int kc = (e >> 9) & 7;
        int n  = e >> 12;
        int k   = kc * 32 + (l >> 4) * 8 + j;
        int col = n * 16 + (l & 15);
        ws[KR_FRAGS + e] = f2h_bits(dense_w[k * ODIM + col]);
    }
}

// ---- main: r7 fused-phase schedule + kc0-in-LDS + wide inline-load window ----
// FROZEN laws (3 spill data points r2/r4+r5/r9 vs clean r0/r6/r7):
//   - NO persistent/carried B-fragment register arrays — spill balloon.
//   - Inline loads consumed in the same (possibly unrolled) body are clean.
// Grid 256 x BM=16 FINAL (r3/r8: per-CU stream rate binds; bytes/block are
// BM-invariant). New vs r7: kc0 streamed from LDS (768->704 KB/step, and the
// x-part starts MFMA-ready after the B4 drain); h-part loop unroll 4->8
// (32 inline loads in the scheduler window — more latency cover).
__global__ __launch_bounds__(THREADS, 4) void lstm_mfma_kernel(
    const float* __restrict__ last_input,  // [4096,128]
    const float* __restrict__ h0,          // [4096,256]
    const float* __restrict__ c0,          // [4096,256]
    const float* __restrict__ bias,        // [1024]
    const float* __restrict__ dense_b,     // [128]
    const ushort* __restrict__ wsro,
    float* __restrict__ out)               // [4096,48,128]
{
    const ushort* KR = wsro;

    __shared__ ushort sA[BM][SA_W];                  // fp16 bits
    __shared__ __align__(16) ushort sDw[D_FRAGS];    // dense weights
    __shared__ __align__(16) ushort sKR0[KR0_FRAGS]; // KR kc0 fragments

    const int t  = threadIdx.x;
    const int w  = t >> 6;          // wave 0..15
    const int l  = t & 63;
    const int cl = l & 15;          // A row within tile / C col
    const int rg = l >> 4;          // C rows 4*rg..+4, k-group
    const int blockRow = blockIdx.x * BM;

    // ---- stage dense weights + KR kc0 into LDS (once) ----
    for (int i = t * 8; i < D_FRAGS; i += THREADS * 8)
        *reinterpret_cast<f16x8*>(&sDw[i]) =
            *reinterpret_cast<const f16x8*>(&wsro[KR_FRAGS + i]);
    for (int c = t; c < KR0_FRAGS / 8; c += THREADS) {
        int n = c >> 6, ll = c & 63;
        *reinterpret_cast<f16x8*>(&sKR0[c * 8]) =
            *reinterpret_cast<const f16x8*>(&wsro[(n * 768 + ll) * 8]);
    }

    // ---- stage x0 (cols 0..127) and h0 (buf1: cols 384..639) ----
    for (int i = t; i < BM * ODIM; i += THREADS) {
        int r = i >> 7, c = i & 127;
        sA[r][c] = f2h_bits(last_input[(blockRow + r) * ODIM + c]);
    }
    for (int i = t; i < BM * UDIM; i += THREADS) {
        int r = i >> 8, c = i & 255;
        sA[r][384 + c] = f2h_bits(h0[(blockRow + r) * UDIM + c]);
    }

    // ---- per-lane state: wave w owns units u = 16*w + cl, rows 4*rg..+4 ----
    const int unit = 16 * w + cl;
    float cstate[4];
    #pragma unroll
    for (int r = 0; r < 4; ++r)
        cstate[r] = c0[(blockRow + 4 * rg + r) * UDIM + unit];

    float bz[4];
    #pragma unroll
    for (int g = 0; g < 4; ++g)
        bz[g] = bias[256 * g + unit];
    const float db = dense_b[16 * (w & 7) + cl];

    __syncthreads();

    // ---- prologue: acc = bias + h-part(h0)  (h0 lives in buf1, base 384) ----
    f32x4 acc[4];
    #pragma unroll
    for (int g = 0; g < 4; ++g)
        acc[g] = (f32x4){bz[g], bz[g], bz[g], bz[g]};

    #pragma unroll 4
    for (int kc = 4; kc < 12; ++kc) {
        const int koff = 384 + (kc - 4) * 32 + rg * 8;
        f16x8 a = *reinterpret_cast<const f16x8*>(&sA[cl][koff]);
        #pragma unroll
        for (int g = 0; g < 4; ++g) {
            const int n = w + 16 * g;
            const int fo = ((n * 12 + kc) * 64 + l) * 8;
            f16x8 b = *reinterpret_cast<const f16x8*>(KR + fo);
            acc[g] = __builtin_amdgcn_mfma_f32_16x16x32_f16(a, b, acc[g], 0, 0, 0);
        }
    }

    for (int s = 0; s < NSTEPS; ++s) {
        const int hb = 128 + 256 * (s & 1);   // h buffer this step's gates write

        // ======== x-part: acc += x(s) @ K  (kc0 from LDS, kc1-3 streamed) ========
        {
            f16x8 a0 = *reinterpret_cast<const f16x8*>(&sA[cl][rg * 8]);
            #pragma unroll
            for (int g = 0; g < 4; ++g) {
                f16x8 b = *reinterpret_cast<const f16x8*>(&sKR0[((w + 16 * g) * 64 + l) * 8]);
                acc[g] = __builtin_amdgcn_mfma_f32_16x16x32_f16(a0, b, acc[g], 0, 0, 0);
            }
        }
        #pragma unroll 3
        for (int kc = 1; kc < 4; ++kc) {
            const int koff = kc * 32 + rg * 8;
            f16x8 a = *reinterpret_cast<const f16x8*>(&sA[cl][koff]);
            #pragma unroll
            for (int g = 0; g < 4; ++g) {
                const int n = w + 16 * g;
                const int fo = ((n * 12 + kc) * 64 + l) * 8;
                f16x8 b = *reinterpret_cast<const f16x8*>(KR + fo);
                acc[g] = __builtin_amdgcn_mfma_f32_16x16x32_f16(a, b, acc[g], 0, 0, 0);
            }
        }

        // ======== gates: h_new -> hbuf[s&1] (no barrier: that buffer's previous
        // readers finished two barriers ago) ========
        #pragma unroll
        for (int r = 0; r < 4; ++r) {
            float iv = sigmoid_f(acc[0][r]);
            float fv = sigmoid_f(acc[1][r]);
            float gv = tanh_f(acc[2][r]);
            float ov = sigmoid_f(acc[3][r]);
            float cn = fv * cstate[r] + iv * gv;
            cstate[r] = cn;
            float hv = ov * tanh_f(cn);
            sA[4 * rg + r][hb + unit] = f2h_bits(hv);
        }
        __syncthreads();   // B2: h_new visible; orders x-part reads vs dense y-writes

        // ======== fused phase: next-step h-part (all waves) + dense (w<8) ========
        f32x4 acc2[4];
        #pragma unroll
        for (int g = 0; g < 4; ++g)
            acc2[g] = (f32x4){bz[g], bz[g], bz[g], bz[g]};

        if (s < NSTEPS - 1) {
            #pragma unroll 8
            for (int kc = 4; kc < 12; ++kc) {
                const int koff = hb + (kc - 4) * 32 + rg * 8;
                f16x8 a = *reinterpret_cast<const f16x8*>(&sA[cl][koff]);
                #pragma unroll
                for (int g = 0; g < 4; ++g) {
                    const int n = w + 16 * g;
                    const int fo = ((n * 12 + kc) * 64 + l) * 8;
                    f16x8 b = *reinterpret_cast<const f16x8*>(KR + fo);
                    acc2[g] = __builtin_amdgcn_mfma_f32_16x16x32_f16(a, b, acc2[g], 0, 0, 0);
                }
            }
        }

        if (w < 8) {
            f32x4 dacc = (f32x4){db, db, db, db};
            #pragma unroll
            for (int kc = 0; kc < 8; ++kc) {
                const int koff = hb + kc * 32 + rg * 8;
                f16x8 ah = *reinterpret_cast<const f16x8*>(&sA[cl][koff]);
                f16x8 b  = *reinterpret_cast<const f16x8*>(&sDw[w * 4096 + kc * 512 + l * 8]);
                dacc = __builtin_amdgcn_mfma_f32_16x16x32_f16(ah, b, dacc, 0, 0, 0);
            }
            #pragma unroll
            for (int r = 0; r < 4; ++r) {
                float y = fmaxf(dacc[r], 0.0f);
                int row = 4 * rg + r;
                out[((size_t)(blockRow + row) * NSTEPS + s) * ODIM + 16 * w + cl] = y;
                sA[row][16 * w + cl] = f2h_bits(y);
            }
        }
        __syncthreads();   // B4: y/x(s+1) ready; hbuf reads done before next rewrite

        #pragma unroll
        for (int g = 0; g < 4; ++g)
            acc[g] = acc2[g];
    }
}

extern "C" void kernel_launch(void* const* d_in, const int* in_sizes, int n_in,
                              void* d_out, int out_size, void* d_ws, size_t ws_size,
                              hipStream_t stream) {
    const float* last_input = (const float*)d_in[0];
    const float* h0         = (const float*)d_in[1];
    const float* c0         = (const float*)d_in[2];
    const float* kernel_w   = (const float*)d_in[3];
    const float* rec_w      = (const float*)d_in[4];
    const float* bias       = (const float*)d_in[5];
    const float* dense_w    = (const float*)d_in[6];
    const float* dense_b    = (const float*)d_in[7];
    float* out  = (float*)d_out;
    ushort* ws  = (ushort*)d_ws;

    const int prep_total = KR_FRAGS + D_FRAGS;
    hipLaunchKernelGGL(prep_weights, dim3((prep_total + 255) / 256), dim3(256), 0, stream,
                       kernel_w, rec_w, dense_w, ws);
    hipLaunchKernelGGL(lstm_mfma_kernel, dim3(NBLOCKS), dim3(THREADS), 0, stream,
                       last_input, h0, c0, bias, dense_b, (const ushort*)ws, out);
}

// Round 11
// 357.169 us; speedup vs baseline: 2.8275x; 2.8275x over previous
//
#include <hip/hip_runtime.h>
#include <hip/hip_bf16.h>

#define UDIM    256
#define ODIM    128
#define ZDIM    1024
#define NSTEPS  48
#define BM      16
#define THREADS 1024
#define NBLOCKS 256   // 4096 / BM

// ws layout in ushort elements — FP16 bits:
//   KR: [0,       393216)   64 tiles x 12 kc x 64 lanes x 8
//   D : [393216,  425984)   8 tiles x 8 kc x 64 lanes x 8
#define KR_FRAGS 393216
#define D_FRAGS  32768
// LDS-cached kc0 of KR: 64 tiles x 64 lanes x 8 ushort = 64 KB
#define KR0_FRAGS 32768

// sA cols: [0,128)=x, [128,384)=h buf0, [384,640)=h buf1, pad to 648
// (row = 1296 B, 16B-aligned so ds_read_b128 stays legal).
#define SA_W 648

typedef _Float16 f16x8 __attribute__((ext_vector_type(8)));
typedef float    f32x4 __attribute__((ext_vector_type(4)));

__device__ __forceinline__ ushort f2h_bits(float v) {
    _Float16 h = (_Float16)v;          // v_cvt_f16_f32, RNE
    return *reinterpret_cast<ushort*>(&h);
}
__device__ __forceinline__ float sigmoid_f(float x) {
    return 1.0f / (1.0f + __expf(-x));
}
__device__ __forceinline__ float tanh_f(float x) {
    return 1.0f - 2.0f / (__expf(2.0f * x) + 1.0f);
}

// ---- prep: pack weights into MFMA B-fragment order, fp16 (round-nearest) ----
__global__ void prep_weights(const float* __restrict__ kernel_w,   // [128,1024]
                             const float* __restrict__ rec_w,      // [256,1024]
                             const float* __restrict__ dense_w,    // [256,128]
                             ushort* __restrict__ ws) {
    int idx = blockIdx.x * blockDim.x + threadIdx.x;
    if (idx < KR_FRAGS) {
        int j  = idx & 7;
        int l  = (idx >> 3) & 63;
        int fc = idx >> 9;          // n*12 + kc
        int kc = fc % 12;
        int n  = fc / 12;
        int k   = kc * 32 + (l >> 4) * 8 + j;
        int col = n * 16 + (l & 15);
        float wv = (k < 128) ? kernel_w[k * ZDIM + col]
                             : rec_w[(k - 128) * ZDIM + col];
        ws[idx] = f2h_bits(wv);
    } else if (idx < KR_FRAGS + D_FRAGS) {
        int e  = idx - KR_FRAGS;
        int j  = e & 7;
        int l  = (e >> 3) & 63;
        int kc = (e >> 9) & 7;
        int n  = e >> 12;
        int k   = kc * 32 + (l >> 4) * 8 + j;
        int col = n * 16 + (l & 15);
        ws[KR_FRAGS + e] = f2h_bits(dense_w[k * ODIM + col]);
    }
}

// ---- main: EXACT r7 champion + kc0-of-KR-in-LDS (the ONLY delta) ----
// Isolation run: r9/r10 each bundled kc0-LDS with a known-risky register
// element (bk4 persistent regs / unroll-8 32-load window). This round has
// none. If FETCH_SIZE still blows up, kc0-LDS is convicted and r7 is final.
// FROZEN laws: no persistent/carried B-fragment register arrays; inline
// loads only; <=16 global loads per unrolled region (r7's clean max).
// Grid 256 x BM=16 FINAL (r3/r8: per-CU stream rate binds).
__global__ __launch_bounds__(THREADS, 4) void lstm_mfma_kernel(
    const float* __restrict__ last_input,  // [4096,128]
    const float* __restrict__ h0,          // [4096,256]
    const float* __restrict__ c0,          // [4096,256]
    const float* __restrict__ bias,        // [1024]
    const float* __restrict__ dense_b,     // [128]
    const ushort* __restrict__ wsro,
    float* __restrict__ out)               // [4096,48,128]
{
    const ushort* KR = wsro;

    __shared__ ushort sA[BM][SA_W];                  // fp16 bits
    __shared__ __align__(16) ushort sDw[D_FRAGS];    // dense weights
    __shared__ __align__(16) ushort sKR0[KR0_FRAGS]; // KR kc0 fragments

    const int t  = threadIdx.x;
    const int w  = t >> 6;          // wave 0..15
    const int l  = t & 63;
    const int cl = l & 15;          // A row within tile / C col
    const int rg = l >> 4;          // C rows 4*rg..+4, k-group
    const int blockRow = blockIdx.x * BM;

    // ---- stage dense weights + KR kc0 into LDS (once) ----
    for (int i = t * 8; i < D_FRAGS; i += THREADS * 8)
        *reinterpret_cast<f16x8*>(&sDw[i]) =
            *reinterpret_cast<const f16x8*>(&wsro[KR_FRAGS + i]);
    for (int c = t; c < KR0_FRAGS / 8; c += THREADS) {
        int n = c >> 6, ll = c & 63;
        *reinterpret_cast<f16x8*>(&sKR0[c * 8]) =
            *reinterpret_cast<const f16x8*>(&wsro[(n * 768 + ll) * 8]);
    }

    // ---- stage x0 (cols 0..127) and h0 (buf1: cols 384..639) ----
    for (int i = t; i < BM * ODIM; i += THREADS) {
        int r = i >> 7, c = i & 127;
        sA[r][c] = f2h_bits(last_input[(blockRow + r) * ODIM + c]);
    }
    for (int i = t; i < BM * UDIM; i += THREADS) {
        int r = i >> 8, c = i & 255;
        sA[r][384 + c] = f2h_bits(h0[(blockRow + r) * UDIM + c]);
    }

    // ---- per-lane state: wave w owns units u = 16*w + cl, rows 4*rg..+4 ----
    const int unit = 16 * w + cl;
    float cstate[4];
    #pragma unroll
    for (int r = 0; r < 4; ++r)
        cstate[r] = c0[(blockRow + 4 * rg + r) * UDIM + unit];

    float bz[4];
    #pragma unroll
    for (int g = 0; g < 4; ++g)
        bz[g] = bias[256 * g + unit];
    const float db = dense_b[16 * (w & 7) + cl];

    __syncthreads();

    // ---- prologue: acc = bias + h-part(h0)  (h0 lives in buf1, base 384) ----
    f32x4 acc[4];
    #pragma unroll
    for (int g = 0; g < 4; ++g)
        acc[g] = (f32x4){bz[g], bz[g], bz[g], bz[g]};

    #pragma unroll 4
    for (int kc = 4; kc < 12; ++kc) {
        const int koff = 384 + (kc - 4) * 32 + rg * 8;
        f16x8 a = *reinterpret_cast<const f16x8*>(&sA[cl][koff]);
        #pragma unroll
        for (int g = 0; g < 4; ++g) {
            const int n = w + 16 * g;
            const int fo = ((n * 12 + kc) * 64 + l) * 8;
            f16x8 b = *reinterpret_cast<const f16x8*>(KR + fo);
            acc[g] = __builtin_amdgcn_mfma_f32_16x16x32_f16(a, b, acc[g], 0, 0, 0);
        }
    }

    for (int s = 0; s < NSTEPS; ++s) {
        const int hb = 128 + 256 * (s & 1);   // h buffer this step's gates write

        // ======== x-part: acc += x(s) @ K ========
        // kc0 from LDS (MFMA-ready right after the B4 drain); kc1-3 streamed
        // (12 inline global loads — within the 16-load clean window).
        {
            f16x8 a0 = *reinterpret_cast<const f16x8*>(&sA[cl][rg * 8]);
            #pragma unroll
            for (int g = 0; g < 4; ++g) {
                f16x8 b = *reinterpret_cast<const f16x8*>(&sKR0[((w + 16 * g) * 64 + l) * 8]);
                acc[g] = __builtin_amdgcn_mfma_f32_16x16x32_f16(a0, b, acc[g], 0, 0, 0);
            }
        }
        #pragma unroll 3
        for (int kc = 1; kc < 4; ++kc) {
            const int koff = kc * 32 + rg * 8;
            f16x8 a = *reinterpret_cast<const f16x8*>(&sA[cl][koff]);
            #pragma unroll
            for (int g = 0; g < 4; ++g) {
                const int n = w + 16 * g;
                const int fo = ((n * 12 + kc) * 64 + l) * 8;
                f16x8 b = *reinterpret_cast<const f16x8*>(KR + fo);
                acc[g] = __builtin_amdgcn_mfma_f32_16x16x32_f16(a, b, acc[g], 0, 0, 0);
            }
        }

        // ======== gates: h_new -> hbuf[s&1] (no barrier: that buffer's previous
        // readers finished two barriers ago) ========
        #pragma unroll
        for (int r = 0; r < 4; ++r) {
            float iv = sigmoid_f(acc[0][r]);
            float fv = sigmoid_f(acc[1][r]);
            float gv = tanh_f(acc[2][r]);
            float ov = sigmoid_f(acc[3][r]);
            float cn = fv * cstate[r] + iv * gv;
            cstate[r] = cn;
            float hv = ov * tanh_f(cn);
            sA[4 * rg + r][hb + unit] = f2h_bits(hv);
        }
        __syncthreads();   // B2: h_new visible; orders x-part reads vs dense y-writes

        // ======== fused phase: next-step h-part (all waves) + dense (w<8) ========
        f32x4 acc2[4];
        #pragma unroll
        for (int g = 0; g < 4; ++g)
            acc2[g] = (f32x4){bz[g], bz[g], bz[g], bz[g]};

        if (s < NSTEPS - 1) {
            #pragma unroll 4
            for (int kc = 4; kc < 12; ++kc) {
                const int koff = hb + (kc - 4) * 32 + rg * 8;
                f16x8 a = *reinterpret_cast<const f16x8*>(&sA[cl][koff]);
                #pragma unroll
                for (int g = 0; g < 4; ++g) {
                    const int n = w + 16 * g;
                    const int fo = ((n * 12 + kc) * 64 + l) * 8;
                    f16x8 b = *reinterpret_cast<const f16x8*>(KR + fo);
                    acc2[g] = __builtin_amdgcn_mfma_f32_16x16x32_f16(a, b, acc2[g], 0, 0, 0);
                }
            }
        }

        if (w < 8) {
            f32x4 dacc = (f32x4){db, db, db, db};
            #pragma unroll
            for (int kc = 0; kc < 8; ++kc) {
                const int koff = hb + kc * 32 + rg * 8;
                f16x8 ah = *reinterpret_cast<const f16x8*>(&sA[cl][koff]);
                f16x8 b  = *reinterpret_cast<const f16x8*>(&sDw[w * 4096 + kc * 512 + l * 8]);
                dacc = __builtin_amdgcn_mfma_f32_16x16x32_f16(ah, b, dacc, 0, 0, 0);
            }
            #pragma unroll
            for (int r = 0; r < 4; ++r) {
                float y = fmaxf(dacc[r], 0.0f);
                int row = 4 * rg + r;
                out[((size_t)(blockRow + row) * NSTEPS + s) * ODIM + 16 * w + cl] = y;
                sA[row][16 * w + cl] = f2h_bits(y);
            }
        }
        __syncthreads();   // B4: y/x(s+1) ready; hbuf reads done before next rewrite

        #pragma unroll
        for (int g = 0; g < 4; ++g)
            acc[g] = acc2[g];
    }
}

extern "C" void kernel_launch(void* const* d_in, const int* in_sizes, int n_in,
                              void* d_out, int out_size, void* d_ws, size_t ws_size,
                              hipStream_t stream) {
    const float* last_input = (const float*)d_in[0];
    const float* h0         = (const float*)d_in[1];
    const float* c0         = (const float*)d_in[2];
    const float* kernel_w   = (const float*)d_in[3];
    const float* rec_w      = (const float*)d_in[4];
    const float* bias       = (const float*)d_in[5];
    const float* dense_w    = (const float*)d_in[6];
    const float* dense_b    = (const float*)d_in[7];
    float* out  = (float*)d_out;
    ushort* ws  = (ushort*)d_ws;

    const int prep_total = KR_FRAGS + D_FRAGS;
    hipLaunchKernelGGL(prep_weights, dim3((prep_total + 255) / 256), dim3(256), 0, stream,
                       kernel_w, rec_w, dense_w, ws);
    hipLaunchKernelGGL(lstm_mfma_kernel, dim3(NBLOCKS), dim3(THREADS), 0, stream,
                       last_input, h0, c0, bias, dense_b, (const ushort*)ws, out);
}